// Round 21
// baseline (644.873 us; speedup 1.0000x reference)
//
#include <hip/hip_runtime.h>
#include <math.h>

#define N_NODES 100000
#define N_EDGES 1600000
#define EP (N_EDGES + N_NODES)   // edges + self-loops = 1,700,000
#define NH 8
#define NC 64
#define NG 64
#define HC 512
#define BCAP 64                               // bucket-CSR capacity (max deg ~35 incl self-loop)
#define NPART 32                              // pooling atomic partitions
#define BPSTR 80                              // fp8 epilogue patch row stride (bytes, 16B-aligned)

typedef unsigned short bf16_t;
typedef unsigned char fp8_t;
typedef __attribute__((ext_vector_type(8))) short short8;
typedef __attribute__((ext_vector_type(4))) float floatx4;
typedef __attribute__((ext_vector_type(2))) float floatx2;

__device__ inline float bf2f(bf16_t u) {
    union { unsigned int i; float f; } x;
    x.i = (unsigned int)u << 16;
    return x.f;
}
__device__ inline bf16_t f2bf(float f) {
    union { float f; unsigned int i; } x;
    x.f = f;
    unsigned int b = x.i;
    return (bf16_t)((b + 0x7fffu + ((b >> 16) & 1u)) >> 16);
}
__device__ inline fp8_t f2fp8(float f) {   // OCP e4m3fn, RNE, HW saturate
    int v = __builtin_amdgcn_cvt_pk_fp8_f32(f, f, 0, false);
    return (fp8_t)v;
}

// async global->LDS, 16B per lane; lds base must be wave-uniform (HW: base + lane*16),
// global source address is PER-LANE.
__device__ inline void ldsload16(const void* g, void* l) {
    __builtin_amdgcn_global_load_lds(
        (const __attribute__((address_space(1))) unsigned int*)g,
        (__attribute__((address_space(3))) unsigned int*)l, 16, 0, 0);
}

// ---------------- fused setup: pack | scatter | W2 transpose | wprep ----------------
// All three phases are mutually independent and all precede k_layer1.
#define NBW2T (HC * HC / 256)                 // 1024
#define FB_PACK ((N_NODES + 255) / 256)       // 391
#define FB_SCAT ((EP + 255) / 256)            // 6642
__global__ void k_setup(const float* __restrict__ x, bf16_t* __restrict__ xb,
                        const int* __restrict__ batch, int* __restrict__ gstart,
                        const int* __restrict__ ei, int* __restrict__ cnt,
                        int* __restrict__ csr,
                        const float* __restrict__ W1, const float* __restrict__ a1s,
                        const float* __restrict__ a1d, float* __restrict__ wprep,
                        const float* __restrict__ W2, bf16_t* __restrict__ W2T) {
    int blk = blockIdx.x;
    if (blk < FB_PACK) {
        // ---- xb packing + graph bounds (complete coverage, no pre-init) ----
        int i = blk * 256 + threadIdx.x;
        if (i < N_NODES) {
            ushort4 p;
            p.x = f2bf(x[i * 3 + 0]);
            p.y = f2bf(x[i * 3 + 1]);
            p.z = f2bf(x[i * 3 + 2]);
            p.w = 0;
            *(ushort4*)&xb[i * 4] = p;
            int b = batch[i];
            if (i == 0) {
                for (int g = 0; g <= b; g++) gstart[g] = 0;
            } else {
                int bp = batch[i - 1];
                if (b != bp)
                    for (int g = bp + 1; g <= b; g++) gstart[g] = i;
            }
            if (i == N_NODES - 1)
                for (int g = b + 1; g <= NG; g++) gstart[g] = N_NODES;
        }
        return;
    }
    blk -= FB_PACK;
    if (blk < FB_SCAT) {
        // ---- bucket-CSR build: ONE pass, no deg/scan chain ----
        int i = blk * 256 + threadIdx.x;
        if (i >= EP) return;
        int s, d;
        if (i < N_EDGES) { s = ei[i]; d = ei[N_EDGES + i]; }
        else { s = i - N_EDGES; d = s; }
        int pos = atomicAdd(&cnt[d], 1);
        csr[d * BCAP + pos] = s;
        return;
    }
    blk -= FB_SCAT;
    if (blk < NBW2T) {
        // ---- W2 transpose to bf16 ----
        int i = blk * 256 + threadIdx.x;
        int n = i >> 9, kp = i & 511;
        int k = (kp & 7) * 64 + (kp >> 3);
        W2T[i] = f2bf(W2[k * HC + n]);
        return;
    }
    // ---- wprep (single block) ----
    int t = threadIdx.x;
    if (t < 48) {
        int isD = t >= 24;
        int tt = t % 24;
        int h = tt / 3, k = tt % 3;
        const float* a = isD ? a1d : a1s;
        float s = 0.f;
        for (int c = 0; c < 64; c++) s += W1[k * HC + h * 64 + c] * a[h * 64 + c];
        wprep[t] = s;
    }
}

// ---------------- layer 1: ONE wave per block (2 dsts, 32 lanes each) ------
// W1 epilogue values are each read once -> direct global (L1/L2-hot 6KB), no LDS stage.
__global__ __launch_bounds__(64) void k_layer1(
    const bf16_t* __restrict__ xb, const int* __restrict__ cnt, const int* __restrict__ csr,
    const float* __restrict__ W1, const float* __restrict__ wprep, const float* __restrict__ b1,
    bf16_t* __restrict__ x1p) {
    __shared__ float wp[48];
    int lane = threadIdx.x;
    if (lane < 48) wp[lane] = wprep[lane];
    __syncthreads();
    int half = lane >> 5, l32 = lane & 31;
    int dst = blockIdx.x * 2 + half;
    int rs = dst * BCAP, re = rs + cnt[dst];
    ushort4 xd4 = *(const ushort4*)&xb[dst * 4];
    float xdx = bf2f(xd4.x), xdy = bf2f(xd4.y), xdz = bf2f(xd4.z);
    float ald[NH];
#pragma unroll
    for (int h = 0; h < NH; h++)
        ald[h] = xdx * wp[24 + h * 3] + xdy * wp[24 + h * 3 + 1] + xdz * wp[24 + h * 3 + 2];
    float den[NH], c0[NH], c1[NH], c2[NH];
#pragma unroll
    for (int h = 0; h < NH; h++) { den[h] = 0.f; c0[h] = 0.f; c1[h] = 0.f; c2[h] = 0.f; }
    for (int base = rs; base < re; base += 32) {
        int e = base + l32;
        if (e < re) {
            int s = csr[e];
            ushort4 sv4 = *(const ushort4*)&xb[s * 4];
            float svx = bf2f(sv4.x), svy = bf2f(sv4.y), svz = bf2f(sv4.z);
#pragma unroll
            for (int h = 0; h < NH; h++) {
                float ev = svx * wp[h * 3] + svy * wp[h * 3 + 1] + svz * wp[h * 3 + 2] + ald[h];
                ev = fmaxf(ev, 0.2f * ev);
                float w = __expf(ev);
                den[h] += w;
                c0[h] += w * svx;
                c1[h] += w * svy;
                c2[h] += w * svz;
            }
        }
    }
#pragma unroll
    for (int h = 0; h < NH; h++) {
#pragma unroll
        for (int off = 1; off < 32; off <<= 1) {
            den[h] += __shfl_xor(den[h], off, 64);
            c0[h] += __shfl_xor(c0[h], off, 64);
            c1[h] += __shfl_xor(c1[h], off, 64);
            c2[h] += __shfl_xor(c2[h], off, 64);
        }
    }
    bf16_t vbA[NH], vbB[NH];
#pragma unroll
    for (int h = 0; h < NH; h++) {
        int colA = h * 64 + l32;
        float vA = c0[h] * W1[colA] + c1[h] * W1[HC + colA] + c2[h] * W1[2 * HC + colA];
        vA = vA / den[h] + b1[colA];
        vA = vA > 0.f ? vA : (__expf(vA) - 1.f);
        vbA[h] = f2bf(vA);
        int colB = colA + 32;
        float vB = c0[h] * W1[colB] + c1[h] * W1[HC + colB] + c2[h] * W1[2 * HC + colB];
        vB = vB / den[h] + b1[colB];
        vB = vB > 0.f ? vB : (__expf(vB) - 1.f);
        vbB[h] = f2bf(vB);
    }
    uint4 oA, oB;
    oA.x = (unsigned int)vbA[0] | ((unsigned int)vbA[1] << 16);
    oA.y = (unsigned int)vbA[2] | ((unsigned int)vbA[3] << 16);
    oA.z = (unsigned int)vbA[4] | ((unsigned int)vbA[5] << 16);
    oA.w = (unsigned int)vbA[6] | ((unsigned int)vbA[7] << 16);
    oB.x = (unsigned int)vbB[0] | ((unsigned int)vbB[1] << 16);
    oB.y = (unsigned int)vbB[2] | ((unsigned int)vbB[3] << 16);
    oB.z = (unsigned int)vbB[4] | ((unsigned int)vbB[5] << 16);
    oB.w = (unsigned int)vbB[6] | ((unsigned int)vbB[7] << 16);
    *(uint4*)&x1p[(size_t)dst * HC + l32 * 8] = oA;
    *(uint4*)&x1p[(size_t)dst * HC + (l32 + 32) * 8] = oB;
}

// ---------------- GEMM2 128x128, BK=64, async staging; h2 OUTPUT IN FP8-e4m3 ----------------
__global__ __launch_bounds__(256) void k_gemm2(const bf16_t* __restrict__ A,
                                               const bf16_t* __restrict__ BT,
                                               fp8_t* __restrict__ Out,
                                               int row_base, int nrows,
                                               const float* __restrict__ a2s,
                                               const float* __restrict__ a2d,
                                               float* __restrict__ al2s,
                                               float* __restrict__ al2d) {
    __shared__ short smem[16384];          // As 8192 | Bs 8192 (128 rows x 64 shorts each)
    short* As = smem;
    short* Bs = smem + 8192;
    int tid = threadIdx.x;
    int lane = tid & 63, wave = tid >> 6;
    int wm = wave & 1, wn = wave >> 1;
    int lm = lane & 15, quad = lane >> 4;
    int gx = blockIdx.x, gy = blockIdx.y;
    int l8 = lane >> 3, lc8 = lane & 7;
    int sw = lc8 ^ l8;                     // swizzled global chunk for this lane
    const bf16_t* ga[4];
    const bf16_t* gb[4];
    short* la[4];
    short* lb[4];
#pragma unroll
    for (int it = 0; it < 4; it++) {
        int ar = gy * 128 + wave * 32 + it * 8 + l8;
        int arc = (ar < nrows) ? ar : 0;   // clamp OOB (rows never stored)
        ga[it] = A + (size_t)(row_base + arc) * HC + sw * 8;
        gb[it] = BT + (size_t)(gx * 128 + wave * 32 + it * 8 + l8) * HC + sw * 8;
        la[it] = As + (wave * 32 + it * 8) * 64;
        lb[it] = Bs + (wave * 32 + it * 8) * 64;
    }

    floatx4 acc[4][4];
#pragma unroll
    for (int mi = 0; mi < 4; mi++)
#pragma unroll
        for (int ni = 0; ni < 4; ni++) acc[mi][ni] = (floatx4){0.f, 0.f, 0.f, 0.f};

    int lmw = lm & 7;  // read-side swizzle key (row & 7)
    for (int k0 = 0; k0 < HC; k0 += 64) {
        __syncthreads();
#pragma unroll
        for (int it = 0; it < 4; it++) ldsload16(ga[it] + k0, la[it]);
#pragma unroll
        for (int it = 0; it < 4; it++) ldsload16(gb[it] + k0, lb[it]);
        __syncthreads();
        short8 af[4][2], bf[4][2];
#pragma unroll
        for (int mi = 0; mi < 4; mi++)
#pragma unroll
            for (int kk = 0; kk < 2; kk++) {
                int pos = (kk * 4 + quad) ^ lmw;
                af[mi][kk] = *(const short8*)&As[(wm * 64 + mi * 16 + lm) * 64 + pos * 8];
            }
#pragma unroll
        for (int ni = 0; ni < 4; ni++)
#pragma unroll
            for (int kk = 0; kk < 2; kk++) {
                int pos = (kk * 4 + quad) ^ lmw;
                bf[ni][kk] = *(const short8*)&Bs[(wn * 64 + ni * 16 + lm) * 64 + pos * 8];
            }
#pragma unroll
        for (int mi = 0; mi < 4; mi++)
#pragma unroll
            for (int ni = 0; ni < 4; ni++) {
                acc[mi][ni] = __builtin_amdgcn_mfma_f32_16x16x32_bf16(af[mi][0], bf[ni][0], acc[mi][ni], 0, 0, 0);
                acc[mi][ni] = __builtin_amdgcn_mfma_f32_16x16x32_bf16(af[mi][1], bf[ni][1], acc[mi][ni], 0, 0, 0);
            }
    }
    // ---- fused al2 from fp32 acc (EXACT logits; unaffected by fp8 h2 storage) ----
    int head = gx * 2 + wn;
    float a2sv[4], a2dv[4];
#pragma unroll
    for (int ni = 0; ni < 4; ni++) {
        int col = gx * 128 + wn * 64 + ni * 16 + lm;
        a2sv[ni] = a2s[col];
        a2dv[ni] = a2d[col];
    }
#pragma unroll
    for (int mi = 0; mi < 4; mi++) {
#pragma unroll
        for (int rg = 0; rg < 4; rg++) {
            int lrow = gy * 128 + wm * 64 + mi * 16 + quad * 4 + rg;
            float ps = 0.f, pd = 0.f;
#pragma unroll
            for (int ni = 0; ni < 4; ni++) {
                float v = acc[mi][ni][rg];
                ps += v * a2sv[ni];
                pd += v * a2dv[ni];
            }
#pragma unroll
            for (int off = 1; off < 16; off <<= 1) {
                ps += __shfl_xor(ps, off, 64);
                pd += __shfl_xor(pd, off, 64);
            }
            if (lrow < nrows && lm == 0) {
                int ar = row_base + lrow;
                al2s[ar * NH + head] = ps;
                al2d[ar * NH + head] = pd;
            }
        }
    }
    // ---- fp8 store via per-wave LDS byte patch (uint4 global stores, 64B/row segments) ----
    // bpatch regions are per-wave-private: only the FIRST barrier (cross-wave smem
    // reuse after the K-loop) is required; in-loop write->read is same-wave program order.
    __syncthreads();
    unsigned char* bpatch = (unsigned char*)smem + wave * (32 * BPSTR);
#pragma unroll
    for (int p = 0; p < 2; p++) {
#pragma unroll
        for (int mih = 0; mih < 2; mih++) {
            int mi = p * 2 + mih;
#pragma unroll
            for (int ni = 0; ni < 4; ni++)
#pragma unroll
                for (int rg = 0; rg < 4; rg++) {
                    int rl = mih * 16 + quad * 4 + rg;
                    bpatch[rl * BPSTR + ni * 16 + lm] = f2fp8(acc[mi][ni][rg]);
                }
        }
        // same-wave LDS write->read in program order
#pragma unroll
        for (int it = 0; it < 2; it++) {
            int idx = it * 64 + lane;
            int rl = idx >> 2, c16 = idx & 3;
            uint4 v = *(uint4*)&bpatch[rl * BPSTR + c16 * 16];
            int lrow = gy * 128 + wm * 64 + p * 32 + rl;
            if (lrow < nrows)
                *(uint4*)&Out[(size_t)lrow * HC + wn * 64 + gx * 128 + c16 * 16] = v;
        }
    }
}

// convert one uint2 (8 fp8 channels) and accumulate with weight w
#define ACC8(v, w) do { floatx2 c_;                                                            \
    c_ = __builtin_amdgcn_cvt_pk_f32_fp8((v).x, false); acc[0] += (w) * c_.x; acc[1] += (w) * c_.y; \
    c_ = __builtin_amdgcn_cvt_pk_f32_fp8((v).x, true);  acc[2] += (w) * c_.x; acc[3] += (w) * c_.y; \
    c_ = __builtin_amdgcn_cvt_pk_f32_fp8((v).y, false); acc[4] += (w) * c_.x; acc[5] += (w) * c_.y; \
    c_ = __builtin_amdgcn_cvt_pk_f32_fp8((v).y, true);  acc[6] += (w) * c_.x; acc[7] += (w) * c_.y; \
} while (0)

// ---------------- layer 2 + pool: ONE wave per block, double-buffered LDS gather ----
// At its pattern roofline: 3 schedule structures (serial, drain-pipe, counted-vmcnt)
// converge at 3.3-3.6 TB/s useful gather. Frozen.
__global__ __launch_bounds__(64) void k_layer2pool(
    const fp8_t* __restrict__ h2lo, const fp8_t* __restrict__ h2hi, int srows,
    const float* __restrict__ al2s, const float* __restrict__ al2d,
    const int* __restrict__ cnt, const int* __restrict__ csr, const float* __restrict__ b2,
    const int* __restrict__ batch, float* __restrict__ poolpart) {
    __shared__ float wlds[528];        // weights h*65+lane / epilogue staging (conflict-free)
    __shared__ int slds[64];           // source ids
    __shared__ __align__(16) fp8_t gbuf[4096];   // two 2KB halves, 4 rows x 512B each
    int lane = threadIdx.x;
    int hme = lane >> 3;
    int hb = hme * 65;
    int dst = blockIdx.x;
    int rs = dst * BCAP, re = rs + cnt[dst];
    float4 d0 = *(const float4*)&al2d[dst * NH];
    float4 d1 = *(const float4*)&al2d[dst * NH + 4];
    float ald[NH] = {d0.x, d0.y, d0.z, d0.w, d1.x, d1.y, d1.z, d1.w};
    float den[NH], acc[8];
#pragma unroll
    for (int h = 0; h < NH; h++) den[h] = 0.f;
#pragma unroll
    for (int q = 0; q < 8; q++) acc[q] = 0.f;
    int lhalf = lane >> 5;       // which of 2 rows this lane fetches per gload
    int l31 = lane & 31;         // 16B chunk within the row
    for (int eb = rs; eb < re; eb += 64) {
        int e = eb + lane;
        int cl = re - eb; if (cl > 64) cl = 64;
        float w[NH];
        int s = 0;
        if (e < re) {
            s = csr[e];
            float4 p0 = *(const float4*)&al2s[s * NH];
            float4 p1 = *(const float4*)&al2s[s * NH + 4];
            float als[NH] = {p0.x, p0.y, p0.z, p0.w, p1.x, p1.y, p1.z, p1.w};
#pragma unroll
            for (int h = 0; h < NH; h++) {
                float ev = als[h] + ald[h];
                ev = fmaxf(ev, 0.2f * ev);
                w[h] = __expf(ev);
                den[h] += w[h];
            }
        } else {
#pragma unroll
            for (int h = 0; h < NH; h++) w[h] = 0.f;
        }
        slds[lane] = s;
#pragma unroll
        for (int h = 0; h < NH; h++) wlds[h * 65 + lane] = w[h];
        // double-buffered gather: batch k in half k&1; issue k+1 before draining k
        int nb = cl >> 2;          // full 4-row batches
        if (nb > 0) {
            // prologue: issue batch 0 into half 0
#pragma unroll
            for (int t = 0; t < 2; t++) {
                int s0 = slds[t * 2 + lhalf];
                const fp8_t* bp = (s0 < srows) ? (h2lo + (size_t)s0 * HC)
                                               : (h2hi + (size_t)(s0 - srows) * HC);
                ldsload16(bp + l31 * 16, &gbuf[t * 1024]);
            }
            for (int k = 0; k < nb; k++) {
                if (k + 1 < nb) {
                    int hoff = ((k + 1) & 1) * 2048;
#pragma unroll
                    for (int t = 0; t < 2; t++) {
                        int s0 = slds[(k + 1) * 4 + t * 2 + lhalf];
                        const fp8_t* bp = (s0 < srows) ? (h2lo + (size_t)s0 * HC)
                                                       : (h2hi + (size_t)(s0 - srows) * HC);
                        ldsload16(bp + l31 * 16, &gbuf[hoff + t * 1024]);
                    }
                    asm volatile("s_waitcnt vmcnt(2)" ::: "memory");
                } else {
                    asm volatile("s_waitcnt vmcnt(0)" ::: "memory");
                }
                __builtin_amdgcn_sched_barrier(0);
                int coff = (k & 1) * 2048;
#pragma unroll
                for (int u = 0; u < 4; u++) {
                    float wA = wlds[hb + k * 4 + u];
                    uint2 vA = *(const uint2*)&gbuf[coff + u * 512 + lane * 8];
                    ACC8(vA, wA);
                }
            }
        }
        for (int j = nb * 4; j < cl; j++) {
            int sA = slds[j];
            float wA = wlds[hb + j];
            const fp8_t* bA = (sA < srows) ? (h2lo + (size_t)sA * HC)
                                           : (h2hi + (size_t)(sA - srows) * HC);
            uint2 vA = *(const uint2*)&bA[lane * 8];
            ACC8(vA, wA);
        }
    }
#pragma unroll
    for (int h = 0; h < NH; h++)
#pragma unroll
        for (int off = 1; off < 64; off <<= 1) den[h] += __shfl_xor(den[h], off, 64);
    float dd = den[0];
#pragma unroll
    for (int h = 1; h < NH; h++) dd = (hme == h) ? den[h] : dd;
    float dinv = 1.0f / dd;
    float4 ba = *(const float4*)&b2[lane * 8];
    float4 bb = *(const float4*)&b2[lane * 8 + 4];
    float bv[8] = {ba.x, ba.y, ba.z, ba.w, bb.x, bb.y, bb.z, bb.w};
    // stage post-ELU values in LDS (swizzled, conflict-free), then atomics in
    // COALESCED (h*64+lane) order — same-wave write->read, no barrier needed
#pragma unroll
    for (int q = 0; q < 8; q++) {
        float v = acc[q] * dinv + bv[q];
        v = v > 0.f ? v : (__expf(v) - 1.f);
        int c = lane * 8 + q;
        wlds[c + (c >> 5)] = v;
    }
    int g = batch[dst];
    float* pp = poolpart + ((size_t)(dst & (NPART - 1)) * NG + g) * HC;
#pragma unroll
    for (int h = 0; h < NH; h++) {
        int c = h * 64 + lane;
        atomicAdd(&pp[c], wlds[c + (c >> 5)]);
    }
}

// ---------------- fused pool-reduce + classifier ----------------
__global__ __launch_bounds__(256) void k_poolcls(const float* __restrict__ poolpart,
                                                 const int* __restrict__ gstart,
                                                 const float* __restrict__ Wc,
                                                 const float* __restrict__ bc,
                                                 float* __restrict__ out) {
    __shared__ float pl[512];
    int g = blockIdx.x, t = threadIdx.x;
    for (int c = t; c < HC; c += 256) {
        float s = 0.f;
        for (int p = 0; p < NPART; p++) s += poolpart[(size_t)p * NG * HC + g * HC + c];
        pl[c] = s;
    }
    __syncthreads();
    if (t < 10) {
        float cnt = fmaxf((float)(gstart[g + 1] - gstart[g]), 1.0f);
        float acc = 0.f;
        for (int k = 0; k < HC; k++) acc += pl[k] * Wc[k * 10 + t];
        out[g * 10 + t] = acc / cnt + bc[t];
    }
}

extern "C" void kernel_launch(void* const* d_in, const int* in_sizes, int n_in,
                              void* d_out, int out_size, void* d_ws, size_t ws_size,
                              hipStream_t stream) {
    const float* x   = (const float*)d_in[0];
    const int*   ei  = (const int*)d_in[1];
    const int*   bat = (const int*)d_in[2];
    const float* W1  = (const float*)d_in[3];
    const float* a1s = (const float*)d_in[4];
    const float* a1d = (const float*)d_in[5];
    const float* b1  = (const float*)d_in[6];
    const float* W2  = (const float*)d_in[7];
    const float* a2s = (const float*)d_in[8];
    const float* a2d = (const float*)d_in[9];
    const float* b2  = (const float*)d_in[10];
    const float* Wc  = (const float*)d_in[11];
    const float* bc  = (const float*)d_in[12];
    float* out = (float*)d_out;

    char* ws = (char*)d_ws;
    size_t off = 0;
    auto alloc = [&](size_t bytes) {
        size_t o = off;
        off += (bytes + 255) & ~(size_t)255;
        return o;
    };
    float*  wprep    = (float*)(ws + alloc(48 * 4));
    int*    cnt      = (int*)(ws + alloc((size_t)N_NODES * 4));
    int*    gstart   = (int*)(ws + alloc(65 * 4));
    bf16_t* xb       = (bf16_t*)(ws + alloc((size_t)N_NODES * 4 * 2));
    int*    csr      = (int*)(ws + alloc((size_t)N_NODES * BCAP * 4));
    bf16_t* W2T      = (bf16_t*)(ws + alloc((size_t)HC * HC * 2));
    bf16_t* x1b      = (bf16_t*)(ws + alloc((size_t)N_NODES * HC * 2));
    float*  al2s     = (float*)(ws + alloc((size_t)N_NODES * NH * 4));
    float*  al2d     = (float*)(ws + alloc((size_t)N_NODES * NH * 4));
    float*  poolpart = (float*)(ws + alloc((size_t)NPART * NG * HC * 4));

    // slice tier: h2 is FP8 (1 byte/elem) — largest slice temp that fits
    size_t rem = (ws_size > off) ? ws_size - off : 0;
    int nslices, srows;
    if (rem >= (size_t)N_NODES * HC)      { nslices = 1;  srows = N_NODES; }
    else if (rem >= (size_t)50000 * HC)   { nslices = 2;  srows = 50000; }
    else if (rem >= (size_t)25000 * HC)   { nslices = 4;  srows = 25000; }
    else if (rem >= (size_t)12500 * HC)   { nslices = 8;  srows = 12500; }
    else                                  { nslices = 16; srows = 6250; }
    fp8_t* T = (fp8_t*)(ws + alloc((size_t)srows * HC));
    fp8_t* h2hi = (fp8_t*)x1b;   // shift-by-one in-place region (byte-indexed)

    hipMemsetAsync(cnt, 0, (size_t)N_NODES * 4, stream);
    hipMemsetAsync(poolpart, 0, (size_t)NPART * NG * HC * 4, stream);

    k_setup<<<FB_PACK + FB_SCAT + NBW2T + 1, 256, 0, stream>>>(
        x, xb, bat, gstart, ei, cnt, csr, W1, a1s, a1d, wprep, W2, W2T);
    k_layer1<<<N_NODES / 2, 64, 0, stream>>>(xb, cnt, csr, W1, wprep, b1, x1b);
    // shift-by-one in-place GEMM (fp8 out): slice 0 -> T; slice i -> bytes of consumed x1 rows.
    for (int s = 0; s < nslices; s++) {
        fp8_t* outp = (s == 0) ? T : (h2hi + (size_t)(s - 1) * srows * HC);
        k_gemm2<<<dim3(4, (srows + 127) / 128), 256, 0, stream>>>(
            x1b, W2T, outp, s * srows, srows, a2s, a2d, al2s, al2d);
    }
    k_layer2pool<<<N_NODES, 64, 0, stream>>>(T, h2hi, srows, al2s, al2d,
                                             cnt, csr, b2, bat, poolpart);
    k_poolcls<<<NG, 256, 0, stream>>>(poolpart, gstart, Wc, bc, out);
}

// Round 22
// 587.641 us; speedup vs baseline: 1.0974x; 1.0974x over previous
//
#include <hip/hip_runtime.h>
#include <math.h>

#define N_NODES 100000
#define N_EDGES 1600000
#define EP (N_EDGES + N_NODES)   // edges + self-loops = 1,700,000
#define NH 8
#define NC 64
#define NG 64
#define HC 512
#define BCAP 64                               // bucket-CSR capacity (max deg ~38 incl self-loop)
#define NPART 32                              // pooling atomic partitions
#define BPSTR 80                              // fp8 epilogue patch row stride (bytes, 16B-aligned)
#define DCHUNK 8                              // dsts per block in layer2pool (register pooling)

typedef unsigned short bf16_t;
typedef unsigned char fp8_t;
typedef __attribute__((ext_vector_type(8))) short short8;
typedef __attribute__((ext_vector_type(4))) float floatx4;
typedef __attribute__((ext_vector_type(2))) float floatx2;

__device__ inline float bf2f(bf16_t u) {
    union { unsigned int i; float f; } x;
    x.i = (unsigned int)u << 16;
    return x.f;
}
__device__ inline bf16_t f2bf(float f) {
    union { float f; unsigned int i; } x;
    x.f = f;
    unsigned int b = x.i;
    return (bf16_t)((b + 0x7fffu + ((b >> 16) & 1u)) >> 16);
}
__device__ inline fp8_t f2fp8(float f) {   // OCP e4m3fn, RNE, HW saturate
    int v = __builtin_amdgcn_cvt_pk_fp8_f32(f, f, 0, false);
    return (fp8_t)v;
}

// async global->LDS, 16B per lane; lds base must be wave-uniform (HW: base + lane*16),
// global source address is PER-LANE.
__device__ inline void ldsload16(const void* g, void* l) {
    __builtin_amdgcn_global_load_lds(
        (const __attribute__((address_space(1))) unsigned int*)g,
        (__attribute__((address_space(3))) unsigned int*)l, 16, 0, 0);
}

// ---------------- fused setup: pack | scatter | W2 transpose | wprep ----------------
#define NBW2T (HC * HC / 256)                 // 1024
#define FB_PACK ((N_NODES + 255) / 256)       // 391
#define FB_SCAT ((EP + 255) / 256)            // 6642
__global__ void k_setup(const float* __restrict__ x, bf16_t* __restrict__ xb,
                        const int* __restrict__ batch, int* __restrict__ gstart,
                        const int* __restrict__ ei, int* __restrict__ cnt,
                        int* __restrict__ csr,
                        const float* __restrict__ W1, const float* __restrict__ a1s,
                        const float* __restrict__ a1d, float* __restrict__ wprep,
                        const float* __restrict__ W2, bf16_t* __restrict__ W2T) {
    int blk = blockIdx.x;
    if (blk < FB_PACK) {
        int i = blk * 256 + threadIdx.x;
        if (i < N_NODES) {
            ushort4 p;
            p.x = f2bf(x[i * 3 + 0]);
            p.y = f2bf(x[i * 3 + 1]);
            p.z = f2bf(x[i * 3 + 2]);
            p.w = 0;
            *(ushort4*)&xb[i * 4] = p;
            int b = batch[i];
            if (i == 0) {
                for (int g = 0; g <= b; g++) gstart[g] = 0;
            } else {
                int bp = batch[i - 1];
                if (b != bp)
                    for (int g = bp + 1; g <= b; g++) gstart[g] = i;
            }
            if (i == N_NODES - 1)
                for (int g = b + 1; g <= NG; g++) gstart[g] = N_NODES;
        }
        return;
    }
    blk -= FB_PACK;
    if (blk < FB_SCAT) {
        int i = blk * 256 + threadIdx.x;
        if (i >= EP) return;
        int s, d;
        if (i < N_EDGES) { s = ei[i]; d = ei[N_EDGES + i]; }
        else { s = i - N_EDGES; d = s; }
        int pos = atomicAdd(&cnt[d], 1);
        csr[d * BCAP + pos] = s;
        return;
    }
    blk -= FB_SCAT;
    if (blk < NBW2T) {
        int i = blk * 256 + threadIdx.x;
        int n = i >> 9, kp = i & 511;
        int k = (kp & 7) * 64 + (kp >> 3);
        W2T[i] = f2bf(W2[k * HC + n]);
        return;
    }
    int t = threadIdx.x;
    if (t < 48) {
        int isD = t >= 24;
        int tt = t % 24;
        int h = tt / 3, k = tt % 3;
        const float* a = isD ? a1d : a1s;
        float s = 0.f;
        for (int c = 0; c < 64; c++) s += W1[k * HC + h * 64 + c] * a[h * 64 + c];
        wprep[t] = s;
    }
}

// ---------------- layer 1: ONE wave per block (2 dsts, 32 lanes each) ------
__global__ __launch_bounds__(64) void k_layer1(
    const bf16_t* __restrict__ xb, const int* __restrict__ cnt, const int* __restrict__ csr,
    const float* __restrict__ W1, const float* __restrict__ wprep, const float* __restrict__ b1,
    bf16_t* __restrict__ x1p) {
    __shared__ float wp[48];
    int lane = threadIdx.x;
    if (lane < 48) wp[lane] = wprep[lane];
    __syncthreads();
    int half = lane >> 5, l32 = lane & 31;
    int dst = blockIdx.x * 2 + half;
    int rs = dst * BCAP, re = rs + cnt[dst];
    ushort4 xd4 = *(const ushort4*)&xb[dst * 4];
    float xdx = bf2f(xd4.x), xdy = bf2f(xd4.y), xdz = bf2f(xd4.z);
    float ald[NH];
#pragma unroll
    for (int h = 0; h < NH; h++)
        ald[h] = xdx * wp[24 + h * 3] + xdy * wp[24 + h * 3 + 1] + xdz * wp[24 + h * 3 + 2];
    float den[NH], c0[NH], c1[NH], c2[NH];
#pragma unroll
    for (int h = 0; h < NH; h++) { den[h] = 0.f; c0[h] = 0.f; c1[h] = 0.f; c2[h] = 0.f; }
    for (int base = rs; base < re; base += 32) {
        int e = base + l32;
        if (e < re) {
            int s = csr[e];
            ushort4 sv4 = *(const ushort4*)&xb[s * 4];
            float svx = bf2f(sv4.x), svy = bf2f(sv4.y), svz = bf2f(sv4.z);
#pragma unroll
            for (int h = 0; h < NH; h++) {
                float ev = svx * wp[h * 3] + svy * wp[h * 3 + 1] + svz * wp[h * 3 + 2] + ald[h];
                ev = fmaxf(ev, 0.2f * ev);
                float w = __expf(ev);
                den[h] += w;
                c0[h] += w * svx;
                c1[h] += w * svy;
                c2[h] += w * svz;
            }
        }
    }
#pragma unroll
    for (int h = 0; h < NH; h++) {
#pragma unroll
        for (int off = 1; off < 32; off <<= 1) {
            den[h] += __shfl_xor(den[h], off, 64);
            c0[h] += __shfl_xor(c0[h], off, 64);
            c1[h] += __shfl_xor(c1[h], off, 64);
            c2[h] += __shfl_xor(c2[h], off, 64);
        }
    }
    bf16_t vbA[NH], vbB[NH];
#pragma unroll
    for (int h = 0; h < NH; h++) {
        int colA = h * 64 + l32;
        float vA = c0[h] * W1[colA] + c1[h] * W1[HC + colA] + c2[h] * W1[2 * HC + colA];
        vA = vA / den[h] + b1[colA];
        vA = vA > 0.f ? vA : (__expf(vA) - 1.f);
        vbA[h] = f2bf(vA);
        int colB = colA + 32;
        float vB = c0[h] * W1[colB] + c1[h] * W1[HC + colB] + c2[h] * W1[2 * HC + colB];
        vB = vB / den[h] + b1[colB];
        vB = vB > 0.f ? vB : (__expf(vB) - 1.f);
        vbB[h] = f2bf(vB);
    }
    uint4 oA, oB;
    oA.x = (unsigned int)vbA[0] | ((unsigned int)vbA[1] << 16);
    oA.y = (unsigned int)vbA[2] | ((unsigned int)vbA[3] << 16);
    oA.z = (unsigned int)vbA[4] | ((unsigned int)vbA[5] << 16);
    oA.w = (unsigned int)vbA[6] | ((unsigned int)vbA[7] << 16);
    oB.x = (unsigned int)vbB[0] | ((unsigned int)vbB[1] << 16);
    oB.y = (unsigned int)vbB[2] | ((unsigned int)vbB[3] << 16);
    oB.z = (unsigned int)vbB[4] | ((unsigned int)vbB[5] << 16);
    oB.w = (unsigned int)vbB[6] | ((unsigned int)vbB[7] << 16);
    *(uint4*)&x1p[(size_t)dst * HC + l32 * 8] = oA;
    *(uint4*)&x1p[(size_t)dst * HC + (l32 + 32) * 8] = oB;
}

// ---------------- GEMM2 128x128, BK=64, async staging; h2 OUTPUT IN FP8-e4m3 ----------------
__global__ __launch_bounds__(256) void k_gemm2(const bf16_t* __restrict__ A,
                                               const bf16_t* __restrict__ BT,
                                               fp8_t* __restrict__ Out,
                                               int row_base, int nrows,
                                               const float* __restrict__ a2s,
                                               const float* __restrict__ a2d,
                                               float* __restrict__ al2s,
                                               float* __restrict__ al2d) {
    __shared__ short smem[16384];          // As 8192 | Bs 8192 (128 rows x 64 shorts each)
    short* As = smem;
    short* Bs = smem + 8192;
    int tid = threadIdx.x;
    int lane = tid & 63, wave = tid >> 6;
    int wm = wave & 1, wn = wave >> 1;
    int lm = lane & 15, quad = lane >> 4;
    int gx = blockIdx.x, gy = blockIdx.y;
    int l8 = lane >> 3, lc8 = lane & 7;
    int sw = lc8 ^ l8;                     // swizzled global chunk for this lane
    const bf16_t* ga[4];
    const bf16_t* gb[4];
    short* la[4];
    short* lb[4];
#pragma unroll
    for (int it = 0; it < 4; it++) {
        int ar = gy * 128 + wave * 32 + it * 8 + l8;
        int arc = (ar < nrows) ? ar : 0;   // clamp OOB (rows never stored)
        ga[it] = A + (size_t)(row_base + arc) * HC + sw * 8;
        gb[it] = BT + (size_t)(gx * 128 + wave * 32 + it * 8 + l8) * HC + sw * 8;
        la[it] = As + (wave * 32 + it * 8) * 64;
        lb[it] = Bs + (wave * 32 + it * 8) * 64;
    }

    floatx4 acc[4][4];
#pragma unroll
    for (int mi = 0; mi < 4; mi++)
#pragma unroll
        for (int ni = 0; ni < 4; ni++) acc[mi][ni] = (floatx4){0.f, 0.f, 0.f, 0.f};

    int lmw = lm & 7;  // read-side swizzle key (row & 7)
    for (int k0 = 0; k0 < HC; k0 += 64) {
        __syncthreads();
#pragma unroll
        for (int it = 0; it < 4; it++) ldsload16(ga[it] + k0, la[it]);
#pragma unroll
        for (int it = 0; it < 4; it++) ldsload16(gb[it] + k0, lb[it]);
        __syncthreads();
        short8 af[4][2], bf[4][2];
#pragma unroll
        for (int mi = 0; mi < 4; mi++)
#pragma unroll
            for (int kk = 0; kk < 2; kk++) {
                int pos = (kk * 4 + quad) ^ lmw;
                af[mi][kk] = *(const short8*)&As[(wm * 64 + mi * 16 + lm) * 64 + pos * 8];
            }
#pragma unroll
        for (int ni = 0; ni < 4; ni++)
#pragma unroll
            for (int kk = 0; kk < 2; kk++) {
                int pos = (kk * 4 + quad) ^ lmw;
                bf[ni][kk] = *(const short8*)&Bs[(wn * 64 + ni * 16 + lm) * 64 + pos * 8];
            }
#pragma unroll
        for (int mi = 0; mi < 4; mi++)
#pragma unroll
            for (int ni = 0; ni < 4; ni++) {
                acc[mi][ni] = __builtin_amdgcn_mfma_f32_16x16x32_bf16(af[mi][0], bf[ni][0], acc[mi][ni], 0, 0, 0);
                acc[mi][ni] = __builtin_amdgcn_mfma_f32_16x16x32_bf16(af[mi][1], bf[ni][1], acc[mi][ni], 0, 0, 0);
            }
    }
    // ---- fused al2 from fp32 acc (EXACT logits; unaffected by fp8 h2 storage) ----
    int head = gx * 2 + wn;
    float a2sv[4], a2dv[4];
#pragma unroll
    for (int ni = 0; ni < 4; ni++) {
        int col = gx * 128 + wn * 64 + ni * 16 + lm;
        a2sv[ni] = a2s[col];
        a2dv[ni] = a2d[col];
    }
#pragma unroll
    for (int mi = 0; mi < 4; mi++) {
#pragma unroll
        for (int rg = 0; rg < 4; rg++) {
            int lrow = gy * 128 + wm * 64 + mi * 16 + quad * 4 + rg;
            float ps = 0.f, pd = 0.f;
#pragma unroll
            for (int ni = 0; ni < 4; ni++) {
                float v = acc[mi][ni][rg];
                ps += v * a2sv[ni];
                pd += v * a2dv[ni];
            }
#pragma unroll
            for (int off = 1; off < 16; off <<= 1) {
                ps += __shfl_xor(ps, off, 64);
                pd += __shfl_xor(pd, off, 64);
            }
            if (lrow < nrows && lm == 0) {
                int ar = row_base + lrow;
                al2s[ar * NH + head] = ps;
                al2d[ar * NH + head] = pd;
            }
        }
    }
    // ---- fp8 store via per-wave LDS byte patch (uint4 global stores, 64B/row segments) ----
    __syncthreads();
    unsigned char* bpatch = (unsigned char*)smem + wave * (32 * BPSTR);
#pragma unroll
    for (int p = 0; p < 2; p++) {
#pragma unroll
        for (int mih = 0; mih < 2; mih++) {
            int mi = p * 2 + mih;
#pragma unroll
            for (int ni = 0; ni < 4; ni++)
#pragma unroll
                for (int rg = 0; rg < 4; rg++) {
                    int rl = mih * 16 + quad * 4 + rg;
                    bpatch[rl * BPSTR + ni * 16 + lm] = f2fp8(acc[mi][ni][rg]);
                }
        }
#pragma unroll
        for (int it = 0; it < 2; it++) {
            int idx = it * 64 + lane;
            int rl = idx >> 2, c16 = idx & 3;
            uint4 v = *(uint4*)&bpatch[rl * BPSTR + c16 * 16];
            int lrow = gy * 128 + wm * 64 + p * 32 + rl;
            if (lrow < nrows)
                *(uint4*)&Out[(size_t)lrow * HC + wn * 64 + gx * 128 + c16 * 16] = v;
        }
    }
}

// convert one uint2 (8 fp8 channels) and accumulate with weight w
#define ACC8(v, w) do { floatx2 c_;                                                            \
    c_ = __builtin_amdgcn_cvt_pk_f32_fp8((v).x, false); acc[0] += (w) * c_.x; acc[1] += (w) * c_.y; \
    c_ = __builtin_amdgcn_cvt_pk_f32_fp8((v).x, true);  acc[2] += (w) * c_.x; acc[3] += (w) * c_.y; \
    c_ = __builtin_amdgcn_cvt_pk_f32_fp8((v).y, false); acc[4] += (w) * c_.x; acc[5] += (w) * c_.y; \
    c_ = __builtin_amdgcn_cvt_pk_f32_fp8((v).y, true);  acc[6] += (w) * c_.x; acc[7] += (w) * c_.y; \
} while (0)

// ---------------- layer 2 + pool: ONE wave, DCHUNK dsts/block, register pooling ----
// Gather pipeline frozen at its pattern roofline. NEW: 8 consecutive dsts per block,
// pool contributions accumulated in registers, ONE atomic flush per graph-segment
// (<=2 per chunk since graphs span ~1562 nodes) -> atomic WRITE traffic / 8.
// No barriers, no cross-wave state: chunking cannot re-trigger R3's straggler coupling,
// and 8-dst work sums have LOWER relative variance than single dsts.
__global__ __launch_bounds__(64) void k_layer2pool(
    const fp8_t* __restrict__ h2lo, const fp8_t* __restrict__ h2hi, int srows,
    const float* __restrict__ al2s, const float* __restrict__ al2d,
    const int* __restrict__ cnt, const int* __restrict__ csr, const float* __restrict__ b2,
    const int* __restrict__ batch, float* __restrict__ poolpart) {
    __shared__ float wlds[528];        // weights h*65+lane / flush staging (conflict-free)
    __shared__ int slds[64];           // source ids
    __shared__ __align__(16) fp8_t gbuf[4096];   // two 2KB halves, 4 rows x 512B each
    int lane = threadIdx.x;
    int hme = lane >> 3;
    int hb = hme * 65;
    int lhalf = lane >> 5;       // which of 2 rows this lane fetches per gload
    int l31 = lane & 31;         // 16B chunk within the row
    float4 ba = *(const float4*)&b2[lane * 8];
    float4 bb = *(const float4*)&b2[lane * 8 + 4];
    float bv[8] = {ba.x, ba.y, ba.z, ba.w, bb.x, bb.y, bb.z, bb.w};
    float pacc[8];
#pragma unroll
    for (int q = 0; q < 8; q++) pacc[q] = 0.f;
    int dst0 = blockIdx.x * DCHUNK;
    int curg = batch[dst0];
    int part = blockIdx.x & (NPART - 1);
    for (int di = 0; di < DCHUNK; di++) {
        int dst = dst0 + di;
        int rs = dst * BCAP, re = rs + cnt[dst];
        float4 d0 = *(const float4*)&al2d[dst * NH];
        float4 d1 = *(const float4*)&al2d[dst * NH + 4];
        float ald[NH] = {d0.x, d0.y, d0.z, d0.w, d1.x, d1.y, d1.z, d1.w};
        float den[NH], acc[8];
#pragma unroll
        for (int h = 0; h < NH; h++) den[h] = 0.f;
#pragma unroll
        for (int q = 0; q < 8; q++) acc[q] = 0.f;
        for (int eb = rs; eb < re; eb += 64) {
            int e = eb + lane;
            int cl = re - eb; if (cl > 64) cl = 64;
            float w[NH];
            int s = 0;
            if (e < re) {
                s = csr[e];
                float4 p0 = *(const float4*)&al2s[s * NH];
                float4 p1 = *(const float4*)&al2s[s * NH + 4];
                float als[NH] = {p0.x, p0.y, p0.z, p0.w, p1.x, p1.y, p1.z, p1.w};
#pragma unroll
                for (int h = 0; h < NH; h++) {
                    float ev = als[h] + ald[h];
                    ev = fmaxf(ev, 0.2f * ev);
                    w[h] = __expf(ev);
                    den[h] += w[h];
                }
            } else {
#pragma unroll
                for (int h = 0; h < NH; h++) w[h] = 0.f;
            }
            slds[lane] = s;
#pragma unroll
            for (int h = 0; h < NH; h++) wlds[h * 65 + lane] = w[h];
            // double-buffered gather: batch k in half k&1; issue k+1 before draining k
            int nb = cl >> 2;          // full 4-row batches
            if (nb > 0) {
#pragma unroll
                for (int t = 0; t < 2; t++) {
                    int s0 = slds[t * 2 + lhalf];
                    const fp8_t* bp = (s0 < srows) ? (h2lo + (size_t)s0 * HC)
                                                   : (h2hi + (size_t)(s0 - srows) * HC);
                    ldsload16(bp + l31 * 16, &gbuf[t * 1024]);
                }
                for (int k = 0; k < nb; k++) {
                    if (k + 1 < nb) {
                        int hoff = ((k + 1) & 1) * 2048;
#pragma unroll
                        for (int t = 0; t < 2; t++) {
                            int s0 = slds[(k + 1) * 4 + t * 2 + lhalf];
                            const fp8_t* bp = (s0 < srows) ? (h2lo + (size_t)s0 * HC)
                                                           : (h2hi + (size_t)(s0 - srows) * HC);
                            ldsload16(bp + l31 * 16, &gbuf[hoff + t * 1024]);
                        }
                        asm volatile("s_waitcnt vmcnt(2)" ::: "memory");
                    } else {
                        asm volatile("s_waitcnt vmcnt(0)" ::: "memory");
                    }
                    __builtin_amdgcn_sched_barrier(0);
                    int coff = (k & 1) * 2048;
#pragma unroll
                    for (int u = 0; u < 4; u++) {
                        float wA = wlds[hb + k * 4 + u];
                        uint2 vA = *(const uint2*)&gbuf[coff + u * 512 + lane * 8];
                        ACC8(vA, wA);
                    }
                }
            }
            for (int j = nb * 4; j < cl; j++) {
                int sA = slds[j];
                float wA = wlds[hb + j];
                const fp8_t* bA = (sA < srows) ? (h2lo + (size_t)sA * HC)
                                               : (h2hi + (size_t)(sA - srows) * HC);
                uint2 vA = *(const uint2*)&bA[lane * 8];
                ACC8(vA, wA);
            }
        }
#pragma unroll
        for (int h = 0; h < NH; h++)
#pragma unroll
            for (int off = 1; off < 64; off <<= 1) den[h] += __shfl_xor(den[h], off, 64);
        float dd = den[0];
#pragma unroll
        for (int h = 1; h < NH; h++) dd = (hme == h) ? den[h] : dd;
        float dinv = 1.0f / dd;
        int g = batch[dst];
        if (g != curg) {
            // flush pacc -> poolpart[curg] (staged via LDS, coalesced atomics)
#pragma unroll
            for (int q = 0; q < 8; q++) {
                int c = lane * 8 + q;
                wlds[c + (c >> 5)] = pacc[q];
            }
            float* pp = poolpart + ((size_t)part * NG + curg) * HC;
#pragma unroll
            for (int h = 0; h < NH; h++) {
                int c = h * 64 + lane;
                atomicAdd(&pp[c], wlds[c + (c >> 5)]);
            }
#pragma unroll
            for (int q = 0; q < 8; q++) pacc[q] = 0.f;
            curg = g;
        }
#pragma unroll
        for (int q = 0; q < 8; q++) {
            float v = acc[q] * dinv + bv[q];
            v = v > 0.f ? v : (__expf(v) - 1.f);
            pacc[q] += v;
        }
    }
    // final flush
#pragma unroll
    for (int q = 0; q < 8; q++) {
        int c = lane * 8 + q;
        wlds[c + (c >> 5)] = pacc[q];
    }
    float* pp = poolpart + ((size_t)part * NG + curg) * HC;
#pragma unroll
    for (int h = 0; h < NH; h++) {
        int c = h * 64 + lane;
        atomicAdd(&pp[c], wlds[c + (c >> 5)]);
    }
}

// ---------------- fused pool-reduce + classifier ----------------
__global__ __launch_bounds__(256) void k_poolcls(const float* __restrict__ poolpart,
                                                 const int* __restrict__ gstart,
                                                 const float* __restrict__ Wc,
                                                 const float* __restrict__ bc,
                                                 float* __restrict__ out) {
    __shared__ float pl[512];
    int g = blockIdx.x, t = threadIdx.x;
    for (int c = t; c < HC; c += 256) {
        float s = 0.f;
        for (int p = 0; p < NPART; p++) s += poolpart[(size_t)p * NG * HC + g * HC + c];
        pl[c] = s;
    }
    __syncthreads();
    if (t < 10) {
        float cnt = fmaxf((float)(gstart[g + 1] - gstart[g]), 1.0f);
        float acc = 0.f;
        for (int k = 0; k < HC; k++) acc += pl[k] * Wc[k * 10 + t];
        out[g * 10 + t] = acc / cnt + bc[t];
    }
}

extern "C" void kernel_launch(void* const* d_in, const int* in_sizes, int n_in,
                              void* d_out, int out_size, void* d_ws, size_t ws_size,
                              hipStream_t stream) {
    const float* x   = (const float*)d_in[0];
    const int*   ei  = (const int*)d_in[1];
    const int*   bat = (const int*)d_in[2];
    const float* W1  = (const float*)d_in[3];
    const float* a1s = (const float*)d_in[4];
    const float* a1d = (const float*)d_in[5];
    const float* b1  = (const float*)d_in[6];
    const float* W2  = (const float*)d_in[7];
    const float* a2s = (const float*)d_in[8];
    const float* a2d = (const float*)d_in[9];
    const float* b2  = (const float*)d_in[10];
    const float* Wc  = (const float*)d_in[11];
    const float* bc  = (const float*)d_in[12];
    float* out = (float*)d_out;

    char* ws = (char*)d_ws;
    size_t off = 0;
    auto alloc = [&](size_t bytes) {
        size_t o = off;
        off += (bytes + 255) & ~(size_t)255;
        return o;
    };
    float*  wprep    = (float*)(ws + alloc(48 * 4));
    int*    cnt      = (int*)(ws + alloc((size_t)N_NODES * 4));
    int*    gstart   = (int*)(ws + alloc(65 * 4));
    bf16_t* xb       = (bf16_t*)(ws + alloc((size_t)N_NODES * 4 * 2));
    int*    csr      = (int*)(ws + alloc((size_t)N_NODES * BCAP * 4));
    bf16_t* W2T      = (bf16_t*)(ws + alloc((size_t)HC * HC * 2));
    bf16_t* x1b      = (bf16_t*)(ws + alloc((size_t)N_NODES * HC * 2));
    float*  al2s     = (float*)(ws + alloc((size_t)N_NODES * NH * 4));
    float*  al2d     = (float*)(ws + alloc((size_t)N_NODES * NH * 4));
    float*  poolpart = (float*)(ws + alloc((size_t)NPART * NG * HC * 4));

    // adaptive slice tier: maximize srows given remaining workspace (fewest slices)
    size_t rem = (ws_size > off) ? ws_size - off : 0;
    size_t rowcap = rem / HC;
    int srows;
    if (rowcap >= (size_t)N_NODES) srows = N_NODES;
    else {
        srows = (int)(rowcap & ~(size_t)127);   // multiple of 128
        if (srows < 6250) srows = 6250;         // prior-tier floor (always fit before)
    }
    int nslices = (N_NODES + srows - 1) / srows;
    fp8_t* T = (fp8_t*)(ws + alloc((size_t)srows * HC));
    fp8_t* h2hi = (fp8_t*)x1b;   // shift-by-one in-place region (byte-indexed)

    hipMemsetAsync(cnt, 0, (size_t)N_NODES * 4, stream);
    hipMemsetAsync(poolpart, 0, (size_t)NPART * NG * HC * 4, stream);

    k_setup<<<FB_PACK + FB_SCAT + NBW2T + 1, 256, 0, stream>>>(
        x, xb, bat, gstart, ei, cnt, csr, W1, a1s, a1d, wprep, W2, W2T);
    k_layer1<<<N_NODES / 2, 64, 0, stream>>>(xb, cnt, csr, W1, wprep, b1, x1b);
    // shift-by-one in-place GEMM (fp8 out): slice 0 -> T; slice i -> bytes of consumed x1 rows.
    for (int s = 0; s < nslices; s++) {
        fp8_t* outp = (s == 0) ? T : (h2hi + (size_t)(s - 1) * srows * HC);
        int nrows = N_NODES - s * srows;
        if (nrows > srows) nrows = srows;
        k_gemm2<<<dim3(4, (nrows + 127) / 128), 256, 0, stream>>>(
            x1b, W2T, outp, s * srows, nrows, a2s, a2d, al2s, al2d);
    }
    k_layer2pool<<<N_NODES / DCHUNK, 64, 0, stream>>>(T, h2hi, srows, al2s, al2d,
                                                      cnt, csr, b2, bat, poolpart);
    k_poolcls<<<NG, 256, 0, stream>>>(poolpart, gstart, Wc, bc, out);
}